// Round 7
// baseline (59.261 us; speedup 1.0000x reference)
//
#include <hip/hip_runtime.h>
#include <math.h>

#define B_N 4096
#define C_N 100
#define D_N 384
#define EPSF 1e-12f
#define NT 10          // class tiles
#define CT 10          // classes per tile
#define NK (D_N / 16)  // 24 k-steps of 16 dims
#define RT 32          // rows per block (R=2 rows per thread)

// tbl layout, CLASS-major (float4 units):
//   tbl4[(c*NK + k)*8 + seg]     = wc  (w2*center), dims k*16 + seg*4 .. +3
//   tbl4[(c*NK + k)*8 + seg + 4] = w2
// -> per-block class slice [c0, c0+CT) is contiguous (CT*3072 B) for LDS staging.

// ---------------- prep (fused): tbl, a2[c], present[c], cdist[c]
__global__ __launch_bounds__(128) void k_prep(const float* __restrict__ centers,
                                              const float* __restrict__ cw,
                                              const int* __restrict__ targets,
                                              float* __restrict__ tbl,
                                              float* __restrict__ a2,
                                              float* __restrict__ cdist,
                                              int* __restrict__ present) {
    int c = blockIdx.x, t = threadIdx.x;
    __shared__ __align__(16) float w2s[D_N];
    __shared__ __align__(16) float cs[D_N];
    __shared__ float sred[2], smin[2];
    __shared__ int ps[2];

    float acc = 0.f;
    for (int d = t; d < D_N; d += 128) {
        float wv = exp2f(cw[c * D_N + d]);
        float ce = centers[c * D_N + d];
        float p  = wv * ce;
        w2s[d] = wv;
        cs[d]  = ce;
        int k = d >> 4, seg = (d >> 2) & 3, e = d & 3;
        int base = ((c * NK + k) * 8 + seg) * 4 + e;
        tbl[base]      = p;   // wc
        tbl[base + 16] = wv;  // w2
        acc = fmaf(p, ce, acc);
    }
    for (int m = 1; m < 64; m <<= 1) acc += __shfl_xor(acc, m, 64);

    int pr = 0;
    for (int i = t; i < B_N; i += 128) pr |= (targets[i] == c) ? 1 : 0;
    pr = __any(pr) ? 1 : 0;

    if ((t & 63) == 0) { sred[t >> 6] = acc; ps[t >> 6] = pr; }
    __syncthreads();   // publishes w2s / cs
    if (t == 0) { a2[c] = sred[0] + sred[1]; present[c] = ps[0] | ps[1]; }

    // cdist[c] = min over other centers j (thread t = j), weights w2s (center c's)
    float v = INFINITY;
    if (t < C_N && t != c) {
        float ad = 0.f;
        const float4* cj = (const float4*)(centers + (size_t)t * D_N);
        const float4* ci = (const float4*)cs;
        const float4* wi = (const float4*)w2s;
        for (int k = 0; k < D_N / 4; k++) {
            float4 a = ci[k], b = cj[k], wv = wi[k];
            float dd;
            dd = a.x - b.x; ad = fmaf(wv.x * dd, dd, ad);
            dd = a.y - b.y; ad = fmaf(wv.y * dd, dd, ad);
            dd = a.z - b.z; ad = fmaf(wv.z * dd, dd, ad);
            dd = a.w - b.w; ad = fmaf(wv.w * dd, dd, ad);
        }
        v = sqrtf(fmaxf(ad, 0.f));
    }
    for (int m = 1; m < 64; m <<= 1) v = fminf(v, __shfl_xor(v, m, 64));
    if ((t & 63) == 0) smin[t >> 6] = v;
    __syncthreads();
    if (t == 0) cdist[c] = fminf(smin[0], smin[1]);
}

// ---------------- main: block = 32 rows x 10 classes, 4 waves, 2 rows/thread.
// wave w owns classes c0+w+4j (nc = 3,3,2,2). lane: slot = l&15, seg = l>>4.
// thread rows: rowbase+slot and rowbase+slot+16. Tables from LDS (broadcast reads),
// each table read feeds BOTH rows -> table LDS traffic halved vs round 6.
__global__ __launch_bounds__(256, 2) void k_main(const float* __restrict__ inputs,
                                                 const int* __restrict__ targets,
                                                 const float* __restrict__ tbl,
                                                 const float* __restrict__ a2,
                                                 const int* __restrict__ present,
                                                 float2* __restrict__ apan) {
    __shared__ __align__(16) float4 tb[CT * NK * 8];   // 30720 B
    __shared__ float sap[4][RT], san[4][RT];

    int tid  = threadIdx.x;
    int w    = tid >> 6;
    int l    = tid & 63;
    int slot = l & 15;
    int seg  = l >> 4;
    int ctile   = blockIdx.x;
    int rowtile = blockIdx.y;
    int c0 = ctile * CT;
    int nc = (CT - w + 3) >> 2;   // 3,3,2,2

    int row0 = rowtile * RT + slot;
    int row1 = row0 + 16;
    int ti0 = targets[row0];
    int ti1 = targets[row1];

    // ---- stage class slice: CT*NK*8 = 2400 float4s, contiguous in global
    {
        const float4* gsrc = (const float4*)tbl + (size_t)c0 * NK * 8;
        for (int q = tid; q < CT * NK * 8; q += 256) tb[q] = gsrc[q];
    }
    __syncthreads();

    const float*  xb0 = inputs + (size_t)row0 * D_N + seg * 4;
    const float*  xb1 = inputs + (size_t)row1 * D_N + seg * 4;
    const float4* tw  = tb + w * NK * 8 + seg;   // class c_local = w+4j at +j*4*NK*8

    float cr0[3], qd0[3], cr1[3], qd1[3];
#pragma unroll
    for (int j = 0; j < 3; j++) { cr0[j] = 0.f; qd0[j] = 0.f; cr1[j] = 0.f; qd1[j] = 0.f; }

#pragma unroll
    for (int k = 0; k < NK; k++) {
        float4 xa = *(const float4*)(xb0 + k * 16);
        float4 xbv = *(const float4*)(xb1 + k * 16);
        float4 xa2 = make_float4(xa.x * xa.x, xa.y * xa.y, xa.z * xa.z, xa.w * xa.w);
        float4 xb2 = make_float4(xbv.x * xbv.x, xbv.y * xbv.y, xbv.z * xbv.z, xbv.w * xbv.w);
#pragma unroll
        for (int j = 0; j < 3; j++) {
            if (j < nc) {
                float4 wcv = tw[j * (4 * NK * 8) + k * 8];       // wc
                float4 w2v = tw[j * (4 * NK * 8) + k * 8 + 4];   // w2
                float a0 = cr0[j], b0 = qd0[j], a1 = cr1[j], b1 = qd1[j];
                a0 = fmaf(xa.x,  wcv.x, a0);
                a0 = fmaf(xa.y,  wcv.y, a0);
                a0 = fmaf(xa.z,  wcv.z, a0);
                a0 = fmaf(xa.w,  wcv.w, a0);
                a1 = fmaf(xbv.x, wcv.x, a1);
                a1 = fmaf(xbv.y, wcv.y, a1);
                a1 = fmaf(xbv.z, wcv.z, a1);
                a1 = fmaf(xbv.w, wcv.w, a1);
                b0 = fmaf(xa2.x, w2v.x, b0);
                b0 = fmaf(xa2.y, w2v.y, b0);
                b0 = fmaf(xa2.z, w2v.z, b0);
                b0 = fmaf(xa2.w, w2v.w, b0);
                b1 = fmaf(xb2.x, w2v.x, b1);
                b1 = fmaf(xb2.y, w2v.y, b1);
                b1 = fmaf(xb2.z, w2v.z, b1);
                b1 = fmaf(xb2.w, w2v.w, b1);
                cr0[j] = a0; qd0[j] = b0; cr1[j] = a1; qd1[j] = b1;
            }
        }
    }

    float vap0 = -INFINITY, vmin0 = INFINITY;
    float vap1 = -INFINITY, vmin1 = INFINITY;
#pragma unroll
    for (int j = 0; j < 3; j++) {
        if (j < nc) {
            int c = c0 + w + 4 * j;
            float s0 = cr0[j], t0 = qd0[j], s1 = cr1[j], t1 = qd1[j];
            s0 += __shfl_xor(s0, 16, 64); s0 += __shfl_xor(s0, 32, 64);
            t0 += __shfl_xor(t0, 16, 64); t0 += __shfl_xor(t0, 32, 64);
            s1 += __shfl_xor(s1, 16, 64); s1 += __shfl_xor(s1, 32, 64);
            t1 += __shfl_xor(t1, 16, 64); t1 += __shfl_xor(t1, 32, 64);
            float av = a2[c];
            float g0 = sqrtf(fmaxf(av - 2.f * s0 + t0, EPSF));
            float g1 = sqrtf(fmaxf(av - 2.f * s1 + t1, EPSF));
            int p = present[c];
            if (c == ti0) vap0 = g0; else if (p) vmin0 = fminf(vmin0, g0);
            if (c == ti1) vap1 = g1; else if (p) vmin1 = fminf(vmin1, g1);
        }
    }

    if (l < 16) {
        sap[w][slot] = vap0;       san[w][slot] = vmin0;
        sap[w][slot + 16] = vap1;  san[w][slot + 16] = vmin1;
    }
    __syncthreads();
    if (tid < RT) {
        float ap = fmaxf(fmaxf(sap[0][tid], sap[1][tid]), fmaxf(sap[2][tid], sap[3][tid]));
        float an = fminf(fminf(san[0][tid], san[1][tid]), fminf(san[2][tid], san[3][tid]));
        apan[(size_t)ctile * B_N + rowtile * RT + tid] = make_float2(ap, an);
    }
}

// ---------------- final: combine 10 class tiles, compute loss, reduce sum
__global__ __launch_bounds__(1024) void k_final(const float2* __restrict__ apan,
                                                const float* __restrict__ cdist,
                                                const int* __restrict__ targets,
                                                float* __restrict__ out) {
    int tid = threadIdx.x;
    float sum = 0.f;
    for (int row = tid; row < B_N; row += 1024) {
        float ap = -INFINITY, an = INFINITY;
#pragma unroll
        for (int t = 0; t < NT; t++) {
            float2 v = apan[(size_t)t * B_N + row];
            ap = fmaxf(ap, v.x);
            an = fminf(an, v.y);
        }
        float cc = cdist[targets[row]];
        sum += (an >= cc) ? ap : (ap - an + cc);
    }
    for (int m = 1; m < 64; m <<= 1) sum += __shfl_xor(sum, m, 64);
    __shared__ float sw[16];
    if ((tid & 63) == 0) sw[tid >> 6] = sum;
    __syncthreads();
    if (tid < 64) {
        float v = (tid < 16) ? sw[tid] : 0.f;
        for (int m = 1; m < 16; m <<= 1) v += __shfl_xor(v, m, 64);
        if (tid == 0) out[0] = v / (float)B_N;
    }
}

extern "C" void kernel_launch(void* const* d_in, const int* in_sizes, int n_in,
                              void* d_out, int out_size, void* d_ws, size_t ws_size,
                              hipStream_t stream) {
    const float* inputs  = (const float*)d_in[0];
    const float* centers = (const float*)d_in[1];
    const float* cw      = (const float*)d_in[2];
    const int*   targets = (const int*)d_in[3];
    (void)in_sizes; (void)n_in; (void)out_size; (void)ws_size;

    char* ws = (char*)d_ws;
    float*  tbl     = (float*)(ws + 0);         // 100*24*8 float4 = 307200 B
    float2* apan    = (float2*)(ws + 307200);   // 10*4096*8 = 327680 B
    float*  a2      = (float*)(ws + 634880);    // 100*4
    float*  cdist   = (float*)(ws + 635392);    // 100*4
    int*    present = (int*)(ws + 635904);      // 100*4

    k_prep<<<C_N, 128, 0, stream>>>(centers, cw, targets, tbl, a2, cdist, present);
    dim3 grid(NT, B_N / RT);   // 10 x 128
    k_main<<<grid, 256, 0, stream>>>(inputs, targets, tbl, a2, present, apan);
    k_final<<<1, 1024, 0, stream>>>(apan, cdist, targets, (float*)d_out);
}

// Round 8
// 46.940 us; speedup vs baseline: 1.2625x; 1.2625x over previous
//
#include <hip/hip_runtime.h>
#include <math.h>

#define B_N 4096
#define C_N 100
#define D_N 384
#define EPSF 1e-12f
#define NT 10          // class tiles
#define CT 10          // classes per tile
#define NK (D_N / 16)  // 24 k-steps of 16 dims
#define KW (NK / 4)    // 6 k-steps per wave
#define RT 32          // rows per block (2 rows per thread)

// tbl layout, CLASS-major (float4 units):
//   tbl4[(c*NK + k)*8 + seg]     = wc  (w2*center), dims k*16 + seg*4 .. +3
//   tbl4[(c*NK + k)*8 + seg + 4] = w2
// -> per-block class slice [c0, c0+CT) is contiguous (CT*3072 B) for LDS staging.

// ---------------- prep (fused): tbl, a2[c], present[c], cdist[c]
__global__ __launch_bounds__(128) void k_prep(const float* __restrict__ centers,
                                              const float* __restrict__ cw,
                                              const int* __restrict__ targets,
                                              float* __restrict__ tbl,
                                              float* __restrict__ a2,
                                              float* __restrict__ cdist,
                                              int* __restrict__ present) {
    int c = blockIdx.x, t = threadIdx.x;
    __shared__ __align__(16) float w2s[D_N];
    __shared__ __align__(16) float cs[D_N];
    __shared__ float sred[2], smin[2];
    __shared__ int ps[2];

    float acc = 0.f;
    for (int d = t; d < D_N; d += 128) {
        float wv = exp2f(cw[c * D_N + d]);
        float ce = centers[c * D_N + d];
        float p  = wv * ce;
        w2s[d] = wv;
        cs[d]  = ce;
        int k = d >> 4, seg = (d >> 2) & 3, e = d & 3;
        int base = ((c * NK + k) * 8 + seg) * 4 + e;
        tbl[base]      = p;   // wc
        tbl[base + 16] = wv;  // w2
        acc = fmaf(p, ce, acc);
    }
    for (int m = 1; m < 64; m <<= 1) acc += __shfl_xor(acc, m, 64);

    int pr = 0;
    for (int i = t; i < B_N; i += 128) pr |= (targets[i] == c) ? 1 : 0;
    pr = __any(pr) ? 1 : 0;

    if ((t & 63) == 0) { sred[t >> 6] = acc; ps[t >> 6] = pr; }
    __syncthreads();   // publishes w2s / cs
    if (t == 0) { a2[c] = sred[0] + sred[1]; present[c] = ps[0] | ps[1]; }

    // cdist[c] = min over other centers j (thread t = j), weights w2s (center c's)
    float v = INFINITY;
    if (t < C_N && t != c) {
        float ad = 0.f;
        const float4* cj = (const float4*)(centers + (size_t)t * D_N);
        const float4* ci = (const float4*)cs;
        const float4* wi = (const float4*)w2s;
        for (int k = 0; k < D_N / 4; k++) {
            float4 a = ci[k], b = cj[k], wv = wi[k];
            float dd;
            dd = a.x - b.x; ad = fmaf(wv.x * dd, dd, ad);
            dd = a.y - b.y; ad = fmaf(wv.y * dd, dd, ad);
            dd = a.z - b.z; ad = fmaf(wv.z * dd, dd, ad);
            dd = a.w - b.w; ad = fmaf(wv.w * dd, dd, ad);
        }
        v = sqrtf(fmaxf(ad, 0.f));
    }
    for (int m = 1; m < 64; m <<= 1) v = fminf(v, __shfl_xor(v, m, 64));
    if ((t & 63) == 0) smin[t >> 6] = v;
    __syncthreads();
    if (t == 0) cdist[c] = fminf(smin[0], smin[1]);
}

// ---------------- main: block = 32 rows x 10 classes, 4 waves.
// K-SPLIT: wave w handles k in [w*KW, w*KW+KW) for ALL 10 classes -> every x float4
// loaded by exactly one thread (no cross-wave duplication). Tables from LDS.
// lane: slot = l&15 (row pair slot, slot+16), seg = l>>4 (dim quarter within k-step).
// Epilogue: cross-wave reduce through LDS aliased onto the (dead) table buffer.
__global__ __launch_bounds__(256, 2) void k_main(const float* __restrict__ inputs,
                                                 const int* __restrict__ targets,
                                                 const float* __restrict__ tbl,
                                                 const float* __restrict__ a2,
                                                 const int* __restrict__ present,
                                                 float2* __restrict__ apan) {
    __shared__ __align__(16) float4 tb[CT * NK * 8];   // 38400 B (aliased in epilogue)

    int tid  = threadIdx.x;
    int w    = tid >> 6;
    int l    = tid & 63;
    int slot = l & 15;
    int seg  = l >> 4;
    int ctile   = blockIdx.x;
    int rowtile = blockIdx.y;
    int c0 = ctile * CT;

    int row0 = rowtile * RT + slot;
    int row1 = row0 + 16;

    // ---- stage class slice: CT*NK*8 = 2400 float4s, contiguous in global
    {
        const float4* gsrc = (const float4*)tbl + (size_t)c0 * NK * 8;
        for (int q = tid; q < CT * NK * 8; q += 256) tb[q] = gsrc[q];
    }
    __syncthreads();

    const float* xb0 = inputs + (size_t)row0 * D_N + seg * 4;
    const float* xb1 = inputs + (size_t)row1 * D_N + seg * 4;

    float cr0[CT], qd0[CT], cr1[CT], qd1[CT];
#pragma unroll
    for (int j = 0; j < CT; j++) { cr0[j] = 0.f; qd0[j] = 0.f; cr1[j] = 0.f; qd1[j] = 0.f; }

#pragma unroll
    for (int kk = 0; kk < KW; kk++) {
        int k = w * KW + kk;
        float4 xa = *(const float4*)(xb0 + k * 16);
        float4 xc = *(const float4*)(xb1 + k * 16);
        float4 xa2 = make_float4(xa.x * xa.x, xa.y * xa.y, xa.z * xa.z, xa.w * xa.w);
        float4 xc2 = make_float4(xc.x * xc.x, xc.y * xc.y, xc.z * xc.z, xc.w * xc.w);
        const float4* tk = tb + k * 8 + seg;
#pragma unroll
        for (int j = 0; j < CT; j++) {
            float4 wcv = tk[j * (NK * 8)];       // wc
            float4 w2v = tk[j * (NK * 8) + 4];   // w2
            float a0 = cr0[j], b0 = qd0[j], a1 = cr1[j], b1 = qd1[j];
            a0 = fmaf(xa.x,  wcv.x, a0);
            a0 = fmaf(xa.y,  wcv.y, a0);
            a0 = fmaf(xa.z,  wcv.z, a0);
            a0 = fmaf(xa.w,  wcv.w, a0);
            a1 = fmaf(xc.x,  wcv.x, a1);
            a1 = fmaf(xc.y,  wcv.y, a1);
            a1 = fmaf(xc.z,  wcv.z, a1);
            a1 = fmaf(xc.w,  wcv.w, a1);
            b0 = fmaf(xa2.x, w2v.x, b0);
            b0 = fmaf(xa2.y, w2v.y, b0);
            b0 = fmaf(xa2.z, w2v.z, b0);
            b0 = fmaf(xa2.w, w2v.w, b0);
            b1 = fmaf(xc2.x, w2v.x, b1);
            b1 = fmaf(xc2.y, w2v.y, b1);
            b1 = fmaf(xc2.z, w2v.z, b1);
            b1 = fmaf(xc2.w, w2v.w, b1);
            cr0[j] = a0; qd0[j] = b0; cr1[j] = a1; qd1[j] = b1;
        }
    }

    // ---- seg-reduce within wave (16-lane groups share (slot,row))
#pragma unroll
    for (int j = 0; j < CT; j++) {
        cr0[j] += __shfl_xor(cr0[j], 16, 64); cr0[j] += __shfl_xor(cr0[j], 32, 64);
        qd0[j] += __shfl_xor(qd0[j], 16, 64); qd0[j] += __shfl_xor(qd0[j], 32, 64);
        cr1[j] += __shfl_xor(cr1[j], 16, 64); cr1[j] += __shfl_xor(cr1[j], 32, 64);
        qd1[j] += __shfl_xor(qd1[j], 16, 64); qd1[j] += __shfl_xor(qd1[j], 32, 64);
    }

    // ---- cross-wave reduce: alias dead table LDS
    __syncthreads();   // all waves done reading tb
    float2* red2 = (float2*)tb;                       // [4][CT][RT] float2 (cr,qd)
    float*  gbuf = (float*)tb + 4 * CT * RT * 2;      // [CT][RT] floats
    if (l < 16) {
#pragma unroll
        for (int j = 0; j < CT; j++) {
            red2[(w * CT + j) * RT + slot]      = make_float2(cr0[j], qd0[j]);
            red2[(w * CT + j) * RT + slot + 16] = make_float2(cr1[j], qd1[j]);
        }
    }
    __syncthreads();

    // combine 4 wave-partials -> g for 320 (class,row) pairs; threads cover 256 + 64
#pragma unroll
    for (int half = 0; half < 2; half++) {
        int p = tid + half * 256;
        if (p < CT * RT) {
            int j = p >> 5, r = p & 31;
            float2 v0 = red2[(0 * CT + j) * RT + r];
            float2 v1 = red2[(1 * CT + j) * RT + r];
            float2 v2 = red2[(2 * CT + j) * RT + r];
            float2 v3 = red2[(3 * CT + j) * RT + r];
            float crt = (v0.x + v1.x) + (v2.x + v3.x);
            float qdt = (v0.y + v1.y) + (v2.y + v3.y);
            float d2 = a2[c0 + j] - 2.f * crt + qdt;
            gbuf[j * RT + r] = sqrtf(fmaxf(d2, EPSF));
        }
    }
    __syncthreads();

    // per-row ap/an over this ctile's classes
    if (tid < RT) {
        int row = rowtile * RT + tid;
        int ti  = targets[row];
        float ap = -INFINITY, an = INFINITY;
#pragma unroll
        for (int j = 0; j < CT; j++) {
            int c = c0 + j;
            float g = gbuf[j * RT + tid];
            if (c == ti) ap = g;
            else if (present[c]) an = fminf(an, g);
        }
        apan[(size_t)ctile * B_N + row] = make_float2(ap, an);
    }
}

// ---------------- final: combine 10 class tiles, compute loss, reduce sum
__global__ __launch_bounds__(1024) void k_final(const float2* __restrict__ apan,
                                                const float* __restrict__ cdist,
                                                const int* __restrict__ targets,
                                                float* __restrict__ out) {
    int tid = threadIdx.x;
    float sum = 0.f;
    for (int row = tid; row < B_N; row += 1024) {
        float ap = -INFINITY, an = INFINITY;
#pragma unroll
        for (int t = 0; t < NT; t++) {
            float2 v = apan[(size_t)t * B_N + row];
            ap = fmaxf(ap, v.x);
            an = fminf(an, v.y);
        }
        float cc = cdist[targets[row]];
        sum += (an >= cc) ? ap : (ap - an + cc);
    }
    for (int m = 1; m < 64; m <<= 1) sum += __shfl_xor(sum, m, 64);
    __shared__ float sw[16];
    if ((tid & 63) == 0) sw[tid >> 6] = sum;
    __syncthreads();
    if (tid < 64) {
        float v = (tid < 16) ? sw[tid] : 0.f;
        for (int m = 1; m < 16; m <<= 1) v += __shfl_xor(v, m, 64);
        if (tid == 0) out[0] = v / (float)B_N;
    }
}

extern "C" void kernel_launch(void* const* d_in, const int* in_sizes, int n_in,
                              void* d_out, int out_size, void* d_ws, size_t ws_size,
                              hipStream_t stream) {
    const float* inputs  = (const float*)d_in[0];
    const float* centers = (const float*)d_in[1];
    const float* cw      = (const float*)d_in[2];
    const int*   targets = (const int*)d_in[3];
    (void)in_sizes; (void)n_in; (void)out_size; (void)ws_size;

    char* ws = (char*)d_ws;
    float*  tbl     = (float*)(ws + 0);         // 100*24*8 float4 = 307200 B
    float2* apan    = (float2*)(ws + 307200);   // 10*4096*8 = 327680 B
    float*  a2      = (float*)(ws + 634880);    // 100*4
    float*  cdist   = (float*)(ws + 635392);    // 100*4
    int*    present = (int*)(ws + 635904);      // 100*4

    k_prep<<<C_N, 128, 0, stream>>>(centers, cw, targets, tbl, a2, cdist, present);
    dim3 grid(NT, B_N / RT);   // 10 x 128 = 1280 blocks
    k_main<<<grid, 256, 0, stream>>>(inputs, targets, tbl, a2, present, apan);
    k_final<<<1, 1024, 0, stream>>>(apan, cdist, targets, (float*)d_out);
}